// Round 1
// baseline (452.101 us; speedup 1.0000x reference)
//
#include <hip/hip_runtime.h>

// Elementwise 16-step spiking-threshold recurrence.
// Math notes:
//  - (v - T)/( |v| + 1 ) > 0  <=>  v > T   (denominator strictly positive),
//    so the division is eliminated entirely.
//  - z is exactly 0.0f or 1.0f, so z*H[t] / z*D[t] are exact products;
//    fmaf(z, -H[t], v) rounds identically to the reference's v - z*H[t].
//  - sign(x): +1 / -1 / 0 (x==0 -> 0, matching jnp.sign).

__global__ __launch_bounds__(256) void invert2_kernel(
    const float* __restrict__ x, float* __restrict__ out, int n4)
{
    constexpr float H[16] = {
        -0.89521986f, 1.8242345f, 1.0888329f, 1.2783841f,
         1.1793505f,  5.402602f,  3.556659f, -0.45232677f,
         1.8296803f,  2.5809617f, 4.8217273f, 2.7070105f,
        -0.76238555f, 3.3387434f, 1.7290733f, 5.140637f };
    constexpr float D[16] = {
        -0.18134391f, -0.07921064f, -0.04980344f, -0.02413579f,
         0.50927377f, -0.0713518f,  -0.64178044f, -0.02694374f,
        -0.06014722f, -0.0580623f,  -1.1322998f,  -0.46733513f,
        -0.05247239f, -0.04035916f, -0.02469978f, -0.01966147f };
    constexpr float T[16] = {
         2.821549f,   2.1506927f,  1.9763926f,  2.5215197f,
        -0.99999964f, -1.4365319f, 0.9995256f,  -1.347566f,
        -2.1773431f, -2.2306669f, -1.4854108f,  0.9888728f,
        -2.9239423f, -3.8899376f, -3.105946f,  -4.132591f };

    const int stride = gridDim.x * blockDim.x;
    const float4* __restrict__ xin = reinterpret_cast<const float4*>(x);
    float4* __restrict__ xout = reinterpret_cast<float4*>(out);

    for (int i = blockIdx.x * blockDim.x + threadIdx.x; i < n4; i += stride) {
        float4 xv = xin[i];
        float in[4] = { xv.x, xv.y, xv.z, xv.w };
        float r[4];
#pragma unroll
        for (int c = 0; c < 4; ++c) {
            const float xx = in[c];
            const float s = (xx > 0.0f) ? 1.0f : ((xx < 0.0f) ? -1.0f : 0.0f);
            float v = fabsf(xx);
            float z = 0.0f;
            float o = 0.0f;
#pragma unroll
            for (int t = 0; t < 16; ++t) {
                v = __builtin_fmaf(z, -H[t], v);   // v -= z*H[t] (exact product)
                z = (v > T[t]) ? 1.0f : 0.0f;      // sign((v-T)/(|v|+1)) == sign(v-T)
                o = __builtin_fmaf(z, D[t], o);    // out += z*D[t] (exact product)
            }
            r[c] = o * s;
        }
        float4 ov = make_float4(r[0], r[1], r[2], r[3]);
        xout[i] = ov;
    }
}

extern "C" void kernel_launch(void* const* d_in, const int* in_sizes, int n_in,
                              void* d_out, int out_size, void* d_ws, size_t ws_size,
                              hipStream_t stream)
{
    const float* x = (const float*)d_in[0];
    float* out = (float*)d_out;

    const int n = in_sizes[0];          // 67,108,864 (divisible by 4)
    const int n4 = n / 4;

    const int block = 256;
    int grid = (n4 + block - 1) / block;
    if (grid > 2048) grid = 2048;       // grid-stride; 32 waves/CU resident

    invert2_kernel<<<grid, block, 0, stream>>>(x, out, n4);
}